// Round 2
// baseline (694.516 us; speedup 1.0000x reference)
//
#include <hip/hip_runtime.h>
#include <hip/hip_bf16.h>
#include <stdint.h>

typedef __hip_bfloat16 bf16;
typedef __attribute__((ext_vector_type(8))) short short8;
typedef __attribute__((ext_vector_type(4))) float f32x4;

#define NWIN 1024
#define NH 16
#define HD 32
#define SHIFT 4

// window row r (= win*64 + token) -> source/dest pixel index in (B,64,64) grid.
// Same formula for gather (roll -4) and scatter (roll +4): they are inverses.
__device__ __forceinline__ int row_to_pixel(int r) {
    int win = r >> 6, t = r & 63;
    int b = win >> 6, wy = (win >> 3) & 7, wx = win & 7;
    int h = ((wy << 3) + (t >> 3) + SHIFT) & 63;
    int w = ((wx << 3) + (t & 7) + SHIFT) & 63;
    return (((b << 6) | h) << 6) | w;
}

__device__ __forceinline__ short f2bf_bits(float f) {
    bf16 h = __float2bfloat16(f);
    return *reinterpret_cast<short*>(&h);
}

// fp32 -> bf16 transpose for weights
__global__ void transpose_f2b(const float* __restrict__ src, short* __restrict__ dst,
                              int K, int N) {
    int idx = blockIdx.x * 256 + threadIdx.x;
    if (idx >= K * N) return;
    int k = idx / N, n = idx - k * N;
    dst[n * K + k] = f2bf_bits(src[idx]);
}

// ---------------- QKV GEMM: A = gathered x fp32 (65536 x 512), B = wqkvT bf16 (1536 x 512) ----------------
__global__ __launch_bounds__(256, 2)
void qkv_gemm(const float* __restrict__ x, const bf16* __restrict__ wT,
              const float* __restrict__ bqkv, bf16* __restrict__ qkv) {
    __shared__ __align__(16) short As[128 * 40];
    __shared__ __align__(16) short Bs[128 * 40];
    const int tid = threadIdx.x;
    const int lane = tid & 63, wave = tid >> 6;
    const int wr = wave >> 1, wc = wave & 1;
    const int m0 = blockIdx.x * 128, n0 = blockIdx.y * 128;

    const float* ag[2];
    const short* bg[2];
    int arow[2], ac8[2];
#pragma unroll
    for (int s = 0; s < 2; ++s) {
        int chunk = tid + s * 256;           // 512 chunks of 8 elems (row-major 128x32)
        int row = chunk >> 2, c8 = (chunk & 3) << 3;
        arow[s] = row; ac8[s] = c8;
        int pix = row_to_pixel(m0 + row);
        ag[s] = x + pix * 512 + c8;
        bg[s] = (const short*)wT + (n0 + row) * 512 + c8;
    }

    f32x4 acc[4][4] = {};
    for (int k0 = 0; k0 < 512; k0 += 32) {
        __syncthreads();
#pragma unroll
        for (int s = 0; s < 2; ++s) {
            float4 f0 = *(const float4*)(ag[s] + k0);
            float4 f1 = *(const float4*)(ag[s] + k0 + 4);
            short8 av;
            av[0] = f2bf_bits(f0.x); av[1] = f2bf_bits(f0.y);
            av[2] = f2bf_bits(f0.z); av[3] = f2bf_bits(f0.w);
            av[4] = f2bf_bits(f1.x); av[5] = f2bf_bits(f1.y);
            av[6] = f2bf_bits(f1.z); av[7] = f2bf_bits(f1.w);
            *(short8*)&As[arow[s] * 40 + ac8[s]] = av;
            *(short8*)&Bs[arow[s] * 40 + ac8[s]] = *(const short8*)(bg[s] + k0);
        }
        __syncthreads();
        const int kk = (lane >> 4) << 3;
        short8 af[4], bfr[4];
#pragma unroll
        for (int mt = 0; mt < 4; ++mt)
            af[mt] = *(const short8*)&As[(wr * 64 + mt * 16 + (lane & 15)) * 40 + kk];
#pragma unroll
        for (int nt = 0; nt < 4; ++nt)
            bfr[nt] = *(const short8*)&Bs[(wc * 64 + nt * 16 + (lane & 15)) * 40 + kk];
#pragma unroll
        for (int mt = 0; mt < 4; ++mt)
#pragma unroll
            for (int nt = 0; nt < 4; ++nt)
                acc[mt][nt] = __builtin_amdgcn_mfma_f32_16x16x32_bf16(af[mt], bfr[nt],
                                                                      acc[mt][nt], 0, 0, 0);
    }

    // epilogue: C/D layout col=lane&15, row=(lane>>4)*4+reg [m89]
#pragma unroll
    for (int mt = 0; mt < 4; ++mt) {
        int rbase = m0 + wr * 64 + mt * 16 + ((lane >> 4) << 2);
#pragma unroll
        for (int nt = 0; nt < 4; ++nt) {
            int c = n0 + wc * 64 + nt * 16 + (lane & 15);
            int which = c >> 9, head = (c >> 5) & 15, d = c & 31;
            float bias = bqkv[c];
            float scale = (which == 0) ? 0.17677669529663689f : 1.0f;
#pragma unroll
            for (int reg = 0; reg < 4; ++reg) {
                int r = rbase + reg;
                int win = r >> 6, t = r & 63;
                float v = (acc[mt][nt][reg] + bias) * scale;
                qkv[(((which * NWIN + win) * NH + head) * 64 + t) * HD + d] = __float2bfloat16(v);
            }
        }
    }
}

// ---------------- attention: one block per (window, head) ----------------
__global__ __launch_bounds__(256, 2)
void attn_kernel(bf16* __restrict__ qkv, const float* __restrict__ relpos) {
    const int win = blockIdx.x, head = blockIdx.y;
    __shared__ __align__(16) short qs[64 * 40];
    __shared__ __align__(16) short ks[64 * 40];
    __shared__ __align__(16) short vT[32 * 72];
    __shared__ float Ss[64 * 65];
    __shared__ __align__(16) short Ps[64 * 72];
    __shared__ float rel[225 * 16];
    const int tid = threadIdx.x, lane = tid & 63, wave = tid >> 6;
    const int base = (win * NH + head) * 2048;
    const short* qg = (const short*)qkv + base;
    const short* kg = qg + NWIN * NH * 2048;
    const short* vg = kg + NWIN * NH * 2048;

    {
        int row = tid >> 2, c8 = (tid & 3) << 3;
        *(short8*)&qs[row * 40 + c8] = *(const short8*)(qg + row * 32 + c8);
        *(short8*)&ks[row * 40 + c8] = *(const short8*)(kg + row * 32 + c8);
        short8 vv = *(const short8*)(vg + row * 32 + c8);
#pragma unroll
        for (int e = 0; e < 8; ++e) vT[(c8 + e) * 72 + row] = vv[e];
    }
    for (int i = tid; i < 225 * 16; i += 256) rel[i] = relpos[i];
    __syncthreads();

    // S = q k^T (q pre-scaled); wave handles 16 q-rows x 64 keys
    {
        const int kk = (lane >> 4) << 3;
        short8 aq = *(const short8*)&qs[(wave * 16 + (lane & 15)) * 40 + kk];
        f32x4 sacc[4];
#pragma unroll
        for (int nt = 0; nt < 4; ++nt) {
            short8 bk = *(const short8*)&ks[(nt * 16 + (lane & 15)) * 40 + kk];
            f32x4 z = {};
            sacc[nt] = __builtin_amdgcn_mfma_f32_16x16x32_bf16(aq, bk, z, 0, 0, 0);
        }
#pragma unroll
        for (int nt = 0; nt < 4; ++nt)
#pragma unroll
            for (int reg = 0; reg < 4; ++reg) {
                int qt = wave * 16 + ((lane >> 4) << 2) + reg;
                int kt = nt * 16 + (lane & 15);
                int idx = ((qt >> 3) - (kt >> 3) + 7) * 15 + ((qt & 7) - (kt & 7) + 7);
                Ss[qt * 65 + kt] = sacc[nt][reg] + rel[idx * 16 + head];
            }
    }
    __syncthreads();

    // fp32 softmax: 4 lanes per row, quad shuffle reduce
    {
        int row = tid >> 2, col0 = (tid & 3) << 4;
        float v[16];
        float m = -3e38f;
#pragma unroll
        for (int e = 0; e < 16; ++e) { v[e] = Ss[row * 65 + col0 + e]; m = fmaxf(m, v[e]); }
        m = fmaxf(m, __shfl_xor(m, 1));
        m = fmaxf(m, __shfl_xor(m, 2));
        float s = 0.f;
#pragma unroll
        for (int e = 0; e < 16; ++e) { v[e] = __expf(v[e] - m); s += v[e]; }
        s += __shfl_xor(s, 1);
        s += __shfl_xor(s, 2);
        float inv = 1.f / s;
#pragma unroll
        for (int e = 0; e < 16; ++e) Ps[row * 72 + col0 + e] = f2bf_bits(v[e] * inv);
    }
    __syncthreads();

    // O = P V : wave -> 16 rows x 32 dims, K=64 in 2 steps
    {
        f32x4 oacc[2] = {};
#pragma unroll
        for (int kstep = 0; kstep < 2; ++kstep) {
            const int kk = kstep * 32 + ((lane >> 4) << 3);
            short8 ap = *(const short8*)&Ps[(wave * 16 + (lane & 15)) * 72 + kk];
#pragma unroll
            for (int nt = 0; nt < 2; ++nt) {
                short8 bv = *(const short8*)&vT[(nt * 16 + (lane & 15)) * 72 + kk];
                oacc[nt] = __builtin_amdgcn_mfma_f32_16x16x32_bf16(ap, bv, oacc[nt], 0, 0, 0);
            }
        }
        short* og = (short*)qkv + base;  // overwrite q slice (disjoint per block)
#pragma unroll
        for (int nt = 0; nt < 2; ++nt)
#pragma unroll
            for (int reg = 0; reg < 4; ++reg) {
                int t = wave * 16 + ((lane >> 4) << 2) + reg;
                int d = nt * 16 + (lane & 15);
                og[t * 32 + d] = f2bf_bits(oacc[nt][reg]);
            }
    }
}

// ---------------- out projection GEMM: A = attn out (q slice), scatter fp32 with roll ----------------
__global__ __launch_bounds__(256, 2)
void out_gemm(const bf16* __restrict__ ain, const bf16* __restrict__ wT,
              const float* __restrict__ bout, float* __restrict__ out) {
    __shared__ __align__(16) short As[128 * 40];
    __shared__ __align__(16) short Bs[128 * 40];
    const int tid = threadIdx.x;
    const int lane = tid & 63, wave = tid >> 6;
    const int wr = wave >> 1, wc = wave & 1;
    const int m0 = blockIdx.x * 128, n0 = blockIdx.y * 128;

    const short* ag[2];
    const short* bg[2];
    int arow[2], ac8[2];
#pragma unroll
    for (int s = 0; s < 2; ++s) {
        int chunk = tid + s * 256;
        int row = chunk >> 2, c8 = (chunk & 3) << 3;
        arow[s] = row; ac8[s] = c8;
        int r = m0 + row, win = r >> 6, t = r & 63;
        // A[r][k]: k = head*32+d -> ain[((win*16+head)*64 + t)*32 + d]; +k0 step = k0*64 elems
        ag[s] = (const short*)ain + win * 32768 + t * 32 + c8;
        bg[s] = (const short*)wT + (n0 + row) * 512 + c8;
    }

    f32x4 acc[4][4] = {};
    for (int k0 = 0; k0 < 512; k0 += 32) {
        __syncthreads();
#pragma unroll
        for (int s = 0; s < 2; ++s) {
            *(short8*)&As[arow[s] * 40 + ac8[s]] = *(const short8*)(ag[s] + k0 * 64);
            *(short8*)&Bs[arow[s] * 40 + ac8[s]] = *(const short8*)(bg[s] + k0);
        }
        __syncthreads();
        const int kk = (lane >> 4) << 3;
        short8 af[4], bfr[4];
#pragma unroll
        for (int mt = 0; mt < 4; ++mt)
            af[mt] = *(const short8*)&As[(wr * 64 + mt * 16 + (lane & 15)) * 40 + kk];
#pragma unroll
        for (int nt = 0; nt < 4; ++nt)
            bfr[nt] = *(const short8*)&Bs[(wc * 64 + nt * 16 + (lane & 15)) * 40 + kk];
#pragma unroll
        for (int mt = 0; mt < 4; ++mt)
#pragma unroll
            for (int nt = 0; nt < 4; ++nt)
                acc[mt][nt] = __builtin_amdgcn_mfma_f32_16x16x32_bf16(af[mt], bfr[nt],
                                                                      acc[mt][nt], 0, 0, 0);
    }

#pragma unroll
    for (int mt = 0; mt < 4; ++mt) {
        int rbase = m0 + wr * 64 + mt * 16 + ((lane >> 4) << 2);
#pragma unroll
        for (int nt = 0; nt < 4; ++nt) {
            int c = n0 + wc * 64 + nt * 16 + (lane & 15);
            float bias = bout[c];
#pragma unroll
            for (int reg = 0; reg < 4; ++reg) {
                int r = rbase + reg;
                int pix = row_to_pixel(r);
                out[pix * 512 + c] = acc[mt][nt][reg] + bias;
            }
        }
    }
}

extern "C" void kernel_launch(void* const* d_in, const int* in_sizes, int n_in,
                              void* d_out, int out_size, void* d_ws, size_t ws_size,
                              hipStream_t stream) {
    const float* x       = (const float*)d_in[0];   // (16,64,64,512) fp32
    const float* w_qkv   = (const float*)d_in[1];   // (512,1536) fp32
    const float* b_qkv   = (const float*)d_in[2];   // (1536,) fp32
    const float* rel_pos = (const float*)d_in[3];   // (225,16) fp32
    const float* w_out   = (const float*)d_in[4];   // (512,512) fp32
    const float* b_out   = (const float*)d_in[5];   // (512,) fp32
    float* out = (float*)d_out;

    bf16* wqkvT  = (bf16*)d_ws;                  // 1536*512 bf16
    bf16* woutT  = wqkvT + 1536 * 512;           // 512*512 bf16
    bf16* qkvbuf = woutT + 512 * 512;            // 3*1024*16*64*32 bf16 (~201 MB)

    transpose_f2b<<<(512 * 1536 + 255) / 256, 256, 0, stream>>>(
        w_qkv, (short*)wqkvT, 512, 1536);
    transpose_f2b<<<(512 * 512 + 255) / 256, 256, 0, stream>>>(
        w_out, (short*)woutT, 512, 512);
    qkv_gemm<<<dim3(512, 12), 256, 0, stream>>>(x, wqkvT, b_qkv, qkvbuf);
    attn_kernel<<<dim3(1024, 16), 256, 0, stream>>>(qkvbuf, rel_pos);
    out_gemm<<<dim3(512, 4), 256, 0, stream>>>(qkvbuf, woutT, b_out, out);
}